// Round 6
// baseline (244.840 us; speedup 1.0000x reference)
//
#include <hip/hip_runtime.h>
#include <stddef.h>

#define CCH 128   // channels
#define VT  32    // vertices per gemm block

typedef unsigned int  uint;
typedef unsigned short ushort;

__device__ __forceinline__ ushort f2bf(float f) {        // RNE float->bf16
    uint b = __float_as_uint(f);
    b += 0x7FFFu + ((b >> 16) & 1u);
    return (ushort)(b >> 16);
}
__device__ __forceinline__ float bflo(uint u) { return __uint_as_float(u << 16); }
__device__ __forceinline__ float bfhi(uint u) { return __uint_as_float(u & 0xFFFF0000u); }

// ---------------- prep: A_t[c][o] = W1[o][c]-W2[o][c], W2_t[c][o] = W2[o][c]
//                  + zero counts/total (replaces memset launch)
__global__ void prep_zero(const float* __restrict__ w,
                          float* __restrict__ A_t, float* __restrict__ W2_t,
                          int* __restrict__ zero_buf, int NZ) {
    int i = blockIdx.x * 256 + threadIdx.x;
    if (i < CCH * CCH) {
        int c = i >> 7, o = i & 127;
        float w2 = w[o * 256 + 128 + c];
        A_t[i]  = w[o * 256 + c] - w2;
        W2_t[i] = w2;
    }
    for (int n = i; n < NZ; n += gridDim.x * 256) zero_buf[n] = 0;
}

// ---------------- transpose x [128][N] -> x_t bf16 [N][128], fused edge histogram
__global__ __launch_bounds__(256) void transpose_hist(
        const float* __restrict__ x, ushort* __restrict__ xtb,
        const int* __restrict__ ridx, int* __restrict__ counts, int N, int E) {
    __shared__ float tile[32][33];
    int n0 = blockIdx.x * 32, c0 = blockIdx.y * 32;
    int tid = threadIdx.x;
    {
        int tx = tid & 31, r = tid >> 5;
        #pragma unroll
        for (int k = 0; k < 4; ++k) {
            int c = k * 8 + r;
            int n = n0 + tx;
            tile[c][tx] = (n < N) ? x[(size_t)(c0 + c) * N + n] : 0.f;
        }
    }
    // fused histogram: this block handles a 128-edge slice (grid-stride)
    {
        int flatb = blockIdx.y * gridDim.x + blockIdx.x;
        int slots = gridDim.x * gridDim.y * 128;
        if (tid < 128)
            for (int e = flatb * 128 + tid; e < E; e += slots)
                atomicAdd(&counts[ridx[e]], 1);
    }
    __syncthreads();
    {
        int n = tid >> 3, c4 = (tid & 7) * 4;
        if (n0 + n < N) {
            ushort4 u;
            u.x = f2bf(tile[c4][n]);
            u.y = f2bf(tile[c4 + 1][n]);
            u.z = f2bf(tile[c4 + 2][n]);
            u.w = f2bf(tile[c4 + 3][n]);
            *(ushort4*)(xtb + (size_t)(n0 + n) * CCH + c0 + c4) = u;
        }
    }
}

// ---------------- CSR build: offsets via wave scan + one atomic per wave
__global__ void make_offsets(const int* __restrict__ counts, int* __restrict__ offs,
                             int* __restrict__ total, int N) {
    int n = blockIdx.x * 256 + threadIdx.x;
    int lane = threadIdx.x & 63;
    int c = (n < N) ? counts[n] : 0;
    int s = c;
    #pragma unroll
    for (int d = 1; d < 64; d <<= 1) {
        int u = __shfl_up(s, d);
        if (lane >= d) s += u;
    }
    int base = 0;
    if (lane == 63) base = atomicAdd(total, s);
    base = __shfl(base, 63);
    if (n < N) offs[n] = base + s - c;          // exclusive start (becomes cursor)
}

// ---------------- CSR build: fill edge lists (offs doubles as cursor -> end)
__global__ void fill_csr(const int* __restrict__ ridx, const int* __restrict__ gidx,
                         int* __restrict__ offs, int* __restrict__ csr, int E) {
    int e = blockIdx.x * 256 + threadIdx.x;
    if (e >= E) return;
    int p = atomicAdd(&offs[ridx[e]], 1);
    csr[p] = gidx[e];
}

// ---------------- gather-mean over bf16 x_t: one wave per vertex, no LDS
__global__ __launch_bounds__(256) void gather_mean(
        const uint2* __restrict__ xtb,      // [N][32] uint2 = bf16x4 quads
        const int*   __restrict__ offs_end, // [N] (end after fill)
        const int*   __restrict__ counts,   // [N]
        const int*   __restrict__ csr,      // [E]
        float4*      __restrict__ gmean4,   // [N][32] float4
        int N) {
    int wave = threadIdx.x >> 6;
    int l = threadIdx.x & 63;
    int lq = l & 31;          // channel quad
    int half = l >> 5;        // edge-pair half
    #pragma unroll
    for (int i = 0; i < 2; ++i) {
        int n = blockIdx.x * 8 + wave * 2 + i;
        if (n >= N) return;   // wave-uniform
        int end = __builtin_amdgcn_readfirstlane(offs_end[n]);
        int deg = __builtin_amdgcn_readfirstlane(counts[n]);
        int off = end - deg;
        float4 acc = make_float4(0.f, 0.f, 0.f, 0.f);
        int k = 0;
        for (; k + 16 <= deg; k += 16) {        // 8 outstanding 8B gathers/lane
            uint2 u[8];
            #pragma unroll
            for (int q = 0; q < 8; ++q) {
                int g = csr[off + k + 2 * q + half];
                u[q] = xtb[(size_t)g * 32 + lq];
            }
            #pragma unroll
            for (int q = 0; q < 8; ++q) {
                acc.x += bflo(u[q].x); acc.y += bfhi(u[q].x);
                acc.z += bflo(u[q].y); acc.w += bfhi(u[q].y);
            }
        }
        for (; k + 8 <= deg; k += 8) {
            uint2 u[4];
            #pragma unroll
            for (int q = 0; q < 4; ++q) {
                int g = csr[off + k + 2 * q + half];
                u[q] = xtb[(size_t)g * 32 + lq];
            }
            #pragma unroll
            for (int q = 0; q < 4; ++q) {
                acc.x += bflo(u[q].x); acc.y += bfhi(u[q].x);
                acc.z += bflo(u[q].y); acc.w += bfhi(u[q].y);
            }
        }
        for (; k + 2 <= deg; k += 2) {
            int g = csr[off + k + half];
            uint2 u = xtb[(size_t)g * 32 + lq];
            acc.x += bflo(u.x); acc.y += bfhi(u.x);
            acc.z += bflo(u.y); acc.w += bfhi(u.y);
        }
        if (k < deg && half == 0) {
            int g = csr[off + k];
            uint2 u = xtb[(size_t)g * 32 + lq];
            acc.x += bflo(u.x); acc.y += bfhi(u.x);
            acc.z += bflo(u.y); acc.w += bfhi(u.y);
        }
        acc.x += __shfl_xor(acc.x, 32);
        acc.y += __shfl_xor(acc.y, 32);
        acc.z += __shfl_xor(acc.z, 32);
        acc.w += __shfl_xor(acc.w, 32);
        float inv = (deg > 0) ? 1.f / (float)deg : 0.f;
        if (half == 0)
            gmean4[(size_t)n * 32 + lq] =
                make_float4(acc.x * inv, acc.y * inv, acc.z * inv, acc.w * inv);
    }
}

// ---------------- gemm: out = mask * leaky(A@x + W2@gmean + bias)
// VT=32: grid ~1563 blocks (6+/CU), one barrier, 16 KB LDS
__global__ __launch_bounds__(256) void gemm_out(
        const float*  __restrict__ x,       // [128][N]
        const float4* __restrict__ gmean4,  // [N][32] float4
        const int*    __restrict__ counts,  // [N]
        const float4* __restrict__ A_t4,    // [c][o] 128x128 as float4
        const float4* __restrict__ W2_t4,   // [c][o] 128x128 as float4
        const float*  __restrict__ bias,    // [128]
        float* __restrict__ out,            // [128][N]
        int N) {
    __shared__ float gt[VT][CCH];           // 16 KB
    int n0 = blockIdx.x * VT;
    int t = threadIdx.x;

    // stage gmean[n0+v][:] -> gt[v][c]  (coalesced float4 both sides)
    #pragma unroll
    for (int k = 0; k < 4; ++k) {
        int idx = k * 256 + t;
        int v = idx >> 5;
        int c4 = idx & 31;
        float4 g = make_float4(0.f, 0.f, 0.f, 0.f);
        if (n0 + v < N) g = gmean4[(size_t)(n0 + v) * 32 + c4];
        *(float4*)&gt[v][c4 * 4] = g;
    }
    __syncthreads();

    int l = t & 31;        // o quad: o = 4l..4l+3
    int w = t >> 5;        // vertex quad: v = 4w..4w+3
    int vb = n0 + 4 * w;
    int sb = (vb + 4 <= N) ? vb : (N - 4);  // safe aligned x base (N%4==0)
    float acc[4][4];
    #pragma unroll
    for (int i = 0; i < 4; ++i)
        #pragma unroll
        for (int j = 0; j < 4; ++j) acc[i][j] = 0.f;

    #pragma unroll 2
    for (int c = 0; c < CCH; ++c) {
        float4 a = A_t4[c * 32 + l];
        float4 b = W2_t4[c * 32 + l];
        float4 xv = *(const float4*)(x + (size_t)c * N + sb);
        float gp[4];
        #pragma unroll
        for (int j = 0; j < 4; ++j) gp[j] = gt[4 * w + j][c];   // 2-way (free)
        const float* ap = (const float*)&a;
        const float* bp = (const float*)&b;
        const float* xp = (const float*)&xv;
        #pragma unroll
        for (int i = 0; i < 4; ++i)
            #pragma unroll
            for (int j = 0; j < 4; ++j)
                acc[i][j] += ap[i] * xp[j] + bp[i] * gp[j];
    }

    // epilogue: + bias, empty-segment mask, leaky relu, float4 stores
    if (vb < N) {                     // N%4==0 -> all 4 valid
        float4 bi = *(const float4*)(bias + 4 * l);
        const float* bp = (const float*)&bi;
        float m[4];
        #pragma unroll
        for (int j = 0; j < 4; ++j) m[j] = (counts[vb + j] > 0) ? 1.f : 0.f;
        #pragma unroll
        for (int i = 0; i < 4; ++i) {
            int o = 4 * l + i;
            float r[4];
            #pragma unroll
            for (int j = 0; j < 4; ++j) {
                float v = (acc[i][j] + bp[i]) * m[j];
                r[j] = (v >= 0.f) ? v : 0.3f * v;
            }
            *(float4*)(out + (size_t)o * N + vb) = make_float4(r[0], r[1], r[2], r[3]);
        }
    }
}

extern "C" void kernel_launch(void* const* d_in, const int* in_sizes, int n_in,
                              void* d_out, int out_size, void* d_ws, size_t ws_size,
                              hipStream_t stream) {
    const float* x      = (const float*)d_in[0];  // [1,128,N]
    const float* weight = (const float*)d_in[1];  // [128,256]
    const float* bias   = (const float*)d_in[2];  // [128]
    const int*   ridx   = (const int*)d_in[3];    // [E]
    const int*   gidx   = (const int*)d_in[4];    // [E]
    float* out = (float*)d_out;

    int N = in_sizes[0] / CCH;   // 50000
    int E = in_sizes[3];         // 800000

    char* ws = (char*)d_ws;
    size_t xtb_bytes = (((size_t)N * CCH * sizeof(ushort)) + 63) & ~(size_t)63;
    size_t n_bytes   = (((size_t)N * sizeof(int)) + 63) & ~(size_t)63;
    size_t csr_bytes = (((size_t)E * sizeof(int)) + 63) & ~(size_t)63;
    size_t w_bytes   = (size_t)CCH * CCH * sizeof(float);

    size_t o = 0;
    ushort* xtb   = (ushort*)(ws + o); o += xtb_bytes;
    int*    counts= (int*)   (ws + o); o += n_bytes;
    int*    total = (int*)   (ws + o); o += 64;
    int*    offs  = (int*)   (ws + o); o += n_bytes;
    int*    csr   = (int*)   (ws + o); o += csr_bytes;
    float*  A_t   = (float*) (ws + o); o += w_bytes;
    float*  W2_t  = (float*) (ws + o); o += w_bytes;
    float*  gmean = (float*) (ws + o);

    // 1. weights prep + zero counts/total
    prep_zero<<<196, 256, 0, stream>>>(weight, A_t, W2_t, counts, N + 16);

    // 2. transpose to bf16 + fused histogram
    dim3 tg((N + 31) / 32, CCH / 32);
    transpose_hist<<<tg, 256, 0, stream>>>(x, xtb, ridx, counts, N, E);

    // 3-4. offsets + CSR fill
    int eblocks = (E + 255) / 256;
    int nblocks = (N + 255) / 256;
    make_offsets<<<nblocks, 256, 0, stream>>>(counts, offs, total, N);
    fill_csr<<<eblocks, 256, 0, stream>>>(ridx, gidx, offs, csr, E);
    // offs[n] is now segment END; start = end - counts[n]

    // 5. gather-mean (bf16 reads, fp32 accumulate)
    gather_mean<<<(N + 7) / 8, 256, 0, stream>>>(
        (const uint2*)xtb, offs, counts, csr, (float4*)gmean, N);

    // 6. dual GEMM + bias + mask + leaky
    gemm_out<<<(N + VT - 1) / VT, 256, 0, stream>>>(
        x, (const float4*)gmean, counts,
        (const float4*)A_t, (const float4*)W2_t, bias, out, N);
}

// Round 7
// 170.832 us; speedup vs baseline: 1.4332x; 1.4332x over previous
//
#include <hip/hip_runtime.h>
#include <stddef.h>

#define CCH 128   // channels

typedef unsigned int  uint;
typedef unsigned short ushort;
typedef short bf16x8 __attribute__((ext_vector_type(8)));
typedef float f32x4  __attribute__((ext_vector_type(4)));

__device__ __forceinline__ ushort f2bf(float f) {        // RNE float->bf16
    uint b = __float_as_uint(f);
    b += 0x7FFFu + ((b >> 16) & 1u);
    return (ushort)(b >> 16);
}
__device__ __forceinline__ float bflo(uint u) { return __uint_as_float(u << 16); }
__device__ __forceinline__ float bfhi(uint u) { return __uint_as_float(u & 0xFFFF0000u); }

// ---------------- prep: W_stack bf16 [o][0:128]=W1-W2, [o][128:256]=W2
//                  + zero counts/total (replaces memset launch)
__global__ void prep_zero(const float* __restrict__ w, ushort* __restrict__ wstb,
                          int* __restrict__ zero_buf, int NZ) {
    int i = blockIdx.x * 256 + threadIdx.x;    // 128 blocks -> 32768
    if (i < CCH * 256) {
        int c = i & 255;
        float v = w[i];
        if (c < 128) v -= w[i + 128];          // w1 - w2 (same row, +128 cols)
        wstb[i] = f2bf(v);
    }
    for (int n = i; n < NZ; n += gridDim.x * 256) zero_buf[n] = 0;
}

// ---------------- transpose x [128][N] -> x_t bf16 [N][128], fused edge histogram
__global__ __launch_bounds__(256) void transpose_hist(
        const float* __restrict__ x, ushort* __restrict__ xtb,
        const int* __restrict__ ridx, int* __restrict__ counts, int N, int E) {
    __shared__ float tile[32][33];
    int n0 = blockIdx.x * 32, c0 = blockIdx.y * 32;
    int tid = threadIdx.x;
    {
        int tx = tid & 31, r = tid >> 5;
        #pragma unroll
        for (int k = 0; k < 4; ++k) {
            int c = k * 8 + r;
            int n = n0 + tx;
            tile[c][tx] = (n < N) ? x[(size_t)(c0 + c) * N + n] : 0.f;
        }
    }
    // fused histogram: this block handles a 128-edge slice (grid-stride)
    {
        int flatb = blockIdx.y * gridDim.x + blockIdx.x;
        int slots = gridDim.x * gridDim.y * 128;
        if (tid < 128)
            for (int e = flatb * 128 + tid; e < E; e += slots)
                atomicAdd(&counts[ridx[e]], 1);
    }
    __syncthreads();
    {
        int n = tid >> 3, c4 = (tid & 7) * 4;
        if (n0 + n < N) {
            ushort4 u;
            u.x = f2bf(tile[c4][n]);
            u.y = f2bf(tile[c4 + 1][n]);
            u.z = f2bf(tile[c4 + 2][n]);
            u.w = f2bf(tile[c4 + 3][n]);
            *(ushort4*)(xtb + (size_t)(n0 + n) * CCH + c0 + c4) = u;
        }
    }
}

// ---------------- CSR build: offsets via wave scan + one atomic per wave
__global__ void make_offsets(const int* __restrict__ counts, int* __restrict__ offs,
                             int* __restrict__ total, int N) {
    int n = blockIdx.x * 256 + threadIdx.x;
    int lane = threadIdx.x & 63;
    int c = (n < N) ? counts[n] : 0;
    int s = c;
    #pragma unroll
    for (int d = 1; d < 64; d <<= 1) {
        int u = __shfl_up(s, d);
        if (lane >= d) s += u;
    }
    int base = 0;
    if (lane == 63) base = atomicAdd(total, s);
    base = __shfl(base, 63);
    if (n < N) offs[n] = base + s - c;          // exclusive start (becomes cursor)
}

// ---------------- CSR build: fill edge lists (offs doubles as cursor -> end)
__global__ void fill_csr(const int* __restrict__ ridx, const int* __restrict__ gidx,
                         int* __restrict__ offs, int* __restrict__ csr, int E) {
    int e = blockIdx.x * 256 + threadIdx.x;
    if (e >= E) return;
    int p = atomicAdd(&offs[ridx[e]], 1);
    csr[p] = gidx[e];
}

// ---------------- gather-mean over bf16 x_t: one wave per vertex, bf16 output
__global__ __launch_bounds__(256) void gather_mean(
        const uint2* __restrict__ xtb,      // [N][32] uint2 = bf16x4 quads
        const int*   __restrict__ offs_end, // [N] (end after fill)
        const int*   __restrict__ counts,   // [N]
        const int*   __restrict__ csr,      // [E]
        ushort*      __restrict__ gmb,      // [N][128] bf16
        int N) {
    int wave = threadIdx.x >> 6;
    int l = threadIdx.x & 63;
    int lq = l & 31;          // channel quad
    int half = l >> 5;        // edge-pair half
    #pragma unroll
    for (int i = 0; i < 2; ++i) {
        int n = blockIdx.x * 8 + wave * 2 + i;
        if (n >= N) return;   // wave-uniform
        int end = __builtin_amdgcn_readfirstlane(offs_end[n]);
        int deg = __builtin_amdgcn_readfirstlane(counts[n]);
        int off = end - deg;
        float4 acc = make_float4(0.f, 0.f, 0.f, 0.f);
        int k = 0;
        for (; k + 16 <= deg; k += 16) {        // 8 outstanding 8B gathers/lane
            uint2 u[8];
            #pragma unroll
            for (int q = 0; q < 8; ++q) {
                int g = csr[off + k + 2 * q + half];
                u[q] = xtb[(size_t)g * 32 + lq];
            }
            #pragma unroll
            for (int q = 0; q < 8; ++q) {
                acc.x += bflo(u[q].x); acc.y += bfhi(u[q].x);
                acc.z += bflo(u[q].y); acc.w += bfhi(u[q].y);
            }
        }
        for (; k + 8 <= deg; k += 8) {
            uint2 u[4];
            #pragma unroll
            for (int q = 0; q < 4; ++q) {
                int g = csr[off + k + 2 * q + half];
                u[q] = xtb[(size_t)g * 32 + lq];
            }
            #pragma unroll
            for (int q = 0; q < 4; ++q) {
                acc.x += bflo(u[q].x); acc.y += bfhi(u[q].x);
                acc.z += bflo(u[q].y); acc.w += bfhi(u[q].y);
            }
        }
        for (; k + 2 <= deg; k += 2) {
            int g = csr[off + k + half];
            uint2 u = xtb[(size_t)g * 32 + lq];
            acc.x += bflo(u.x); acc.y += bfhi(u.x);
            acc.z += bflo(u.y); acc.w += bfhi(u.y);
        }
        if (k < deg && half == 0) {
            int g = csr[off + k];
            uint2 u = xtb[(size_t)g * 32 + lq];
            acc.x += bflo(u.x); acc.y += bfhi(u.x);
            acc.z += bflo(u.y); acc.w += bfhi(u.y);
        }
        acc.x += __shfl_xor(acc.x, 32);
        acc.y += __shfl_xor(acc.y, 32);
        acc.z += __shfl_xor(acc.z, 32);
        acc.w += __shfl_xor(acc.w, 32);
        float inv = (deg > 0) ? 1.f / (float)deg : 0.f;
        if (half == 0) {
            ushort4 r;
            r.x = f2bf(acc.x * inv);
            r.y = f2bf(acc.y * inv);
            r.z = f2bf(acc.z * inv);
            r.w = f2bf(acc.w * inv);
            *(ushort4*)(gmb + (size_t)n * CCH + lq * 4) = r;
        }
    }
}

// ---------------- MFMA gemm: out = mask * leaky(W_stack @ [x;gmean] + bias)
// N_TILE=64, 4 waves, each wave: 16 n-cols x 128 o-rows, K=256. No LDS, no barrier.
__global__ __launch_bounds__(256) void gemm_mfma(
        const ushort* __restrict__ wstb,    // [128][256] bf16
        const ushort* __restrict__ xtb,     // [N][128] bf16  (K 0..127)
        const ushort* __restrict__ gmb,     // [N][128] bf16  (K 128..255)
        const int*    __restrict__ counts,  // [N]
        const float*  __restrict__ bias,    // [128]
        float* __restrict__ out,            // [128][N]
        int N) {
    int t = threadIdx.x;
    int wv = t >> 6;       // wave 0..3 -> n-frag
    int l  = t & 63;
    int l15 = l & 15;      // A: M-row / B: N-col / D: N-col
    int lk  = l >> 4;      // k-group (0..3)
    int n = blockIdx.x * 64 + wv * 16 + l15;
    int nc = (n < N) ? n : (N - 1);          // clamped for loads

    f32x4 acc[8];
    #pragma unroll
    for (int mf = 0; mf < 8; ++mf) acc[mf] = (f32x4){0.f, 0.f, 0.f, 0.f};

    const ushort* brow_x = xtb + (size_t)nc * CCH + lk * 8;
    const ushort* brow_g = gmb + (size_t)nc * CCH + lk * 8;
    const ushort* arow   = wstb + (size_t)l15 * 256 + lk * 8;

    #pragma unroll
    for (int ks = 0; ks < 8; ++ks) {
        const ushort* bp = (ks < 4) ? (brow_x + ks * 32) : (brow_g + (ks - 4) * 32);
        bf16x8 b = *(const bf16x8*)bp;
        #pragma unroll
        for (int mf = 0; mf < 8; ++mf) {
            bf16x8 a = *(const bf16x8*)(arow + (size_t)mf * 16 * 256 + ks * 32);
            acc[mf] = __builtin_amdgcn_mfma_f32_16x16x32_bf16(a, b, acc[mf], 0, 0, 0);
        }
    }

    // epilogue: D row(o) = mf*16 + lk*4 + r, col(n) = lane&15
    if (n < N) {
        float m = (counts[n] > 0) ? 1.f : 0.f;
        #pragma unroll
        for (int mf = 0; mf < 8; ++mf) {
            #pragma unroll
            for (int r = 0; r < 4; ++r) {
                int o = mf * 16 + lk * 4 + r;
                float v = (acc[mf][r] + bias[o]) * m;
                v = (v >= 0.f) ? v : 0.3f * v;
                out[(size_t)o * N + n] = v;
            }
        }
    }
}

extern "C" void kernel_launch(void* const* d_in, const int* in_sizes, int n_in,
                              void* d_out, int out_size, void* d_ws, size_t ws_size,
                              hipStream_t stream) {
    const float* x      = (const float*)d_in[0];  // [1,128,N]
    const float* weight = (const float*)d_in[1];  // [128,256]
    const float* bias   = (const float*)d_in[2];  // [128]
    const int*   ridx   = (const int*)d_in[3];    // [E]
    const int*   gidx   = (const int*)d_in[4];    // [E]
    float* out = (float*)d_out;

    int N = in_sizes[0] / CCH;   // 50000
    int E = in_sizes[3];         // 800000

    char* ws = (char*)d_ws;
    size_t xtb_bytes = (((size_t)N * CCH * sizeof(ushort)) + 63) & ~(size_t)63;
    size_t n_bytes   = (((size_t)N * sizeof(int)) + 63) & ~(size_t)63;
    size_t csr_bytes = (((size_t)E * sizeof(int)) + 63) & ~(size_t)63;
    size_t w_bytes   = (((size_t)CCH * 256 * sizeof(ushort)) + 63) & ~(size_t)63;

    size_t o = 0;
    ushort* xtb   = (ushort*)(ws + o); o += xtb_bytes;
    int*    counts= (int*)   (ws + o); o += n_bytes;
    int*    total = (int*)   (ws + o); o += 64;
    int*    offs  = (int*)   (ws + o); o += n_bytes;
    int*    csr   = (int*)   (ws + o); o += csr_bytes;
    ushort* wstb  = (ushort*)(ws + o); o += w_bytes;
    ushort* gmb   = (ushort*)(ws + o);

    // 1. weights prep (bf16 W_stack) + zero counts/total
    prep_zero<<<128, 256, 0, stream>>>(weight, wstb, counts, N + 16);

    // 2. transpose to bf16 + fused histogram
    dim3 tg((N + 31) / 32, CCH / 32);
    transpose_hist<<<tg, 256, 0, stream>>>(x, xtb, ridx, counts, N, E);

    // 3-4. offsets + CSR fill
    int eblocks = (E + 255) / 256;
    int nblocks = (N + 255) / 256;
    make_offsets<<<nblocks, 256, 0, stream>>>(counts, offs, total, N);
    fill_csr<<<eblocks, 256, 0, stream>>>(ridx, gidx, offs, csr, E);
    // offs[n] is now segment END; start = end - counts[n]

    // 5. gather-mean (bf16 reads, fp32 accumulate, bf16 output)
    gather_mean<<<(N + 7) / 8, 256, 0, stream>>>(
        (const uint2*)xtb, offs, counts, csr, gmb, N);

    // 6. single bf16 MFMA GEMM + bias + mask + leaky
    gemm_mfma<<<(N + 63) / 64, 256, 0, stream>>>(
        wstb, xtb, gmb, counts, bias, out, N);
}

// Round 8
// 166.160 us; speedup vs baseline: 1.4735x; 1.0281x over previous
//
#include <hip/hip_runtime.h>
#include <stddef.h>

#define CCH 128   // channels

typedef unsigned int  uint;
typedef unsigned short ushort;
typedef short bf16x8 __attribute__((ext_vector_type(8)));
typedef float f32x4  __attribute__((ext_vector_type(4)));

__device__ __forceinline__ ushort f2bf(float f) {        // RNE float->bf16
    uint b = __float_as_uint(f);
    b += 0x7FFFu + ((b >> 16) & 1u);
    return (ushort)(b >> 16);
}
__device__ __forceinline__ float bflo(uint u) { return __uint_as_float(u << 16); }
__device__ __forceinline__ float bfhi(uint u) { return __uint_as_float(u & 0xFFFF0000u); }

// ---------------- prep: W_stack bf16 [o][0:128]=W1-W2, [o][128:256]=W2
//                  + zero counts/total (replaces memset launch)
__global__ void prep_zero(const float* __restrict__ w, ushort* __restrict__ wstb,
                          int* __restrict__ zero_buf, int NZ) {
    int i = blockIdx.x * 256 + threadIdx.x;    // 128 blocks -> 32768
    if (i < CCH * 256) {
        int c = i & 255;
        float v = w[i];
        if (c < 128) v -= w[i + 128];          // w1 - w2 (same row, +128 cols)
        wstb[i] = f2bf(v);
    }
    for (int n = i; n < NZ; n += gridDim.x * 256) zero_buf[n] = 0;
}

// ---------------- transpose x [128][N] -> x_t bf16 [N][128], fused edge histogram
__global__ __launch_bounds__(256) void transpose_hist(
        const float* __restrict__ x, ushort* __restrict__ xtb,
        const int* __restrict__ ridx, int* __restrict__ counts, int N, int E) {
    __shared__ float tile[32][33];
    int n0 = blockIdx.x * 32, c0 = blockIdx.y * 32;
    int tid = threadIdx.x;
    {
        int tx = tid & 31, r = tid >> 5;
        #pragma unroll
        for (int k = 0; k < 4; ++k) {
            int c = k * 8 + r;
            int n = n0 + tx;
            tile[c][tx] = (n < N) ? x[(size_t)(c0 + c) * N + n] : 0.f;
        }
    }
    // fused histogram: this block handles a 128-edge slice (grid-stride)
    {
        int flatb = blockIdx.y * gridDim.x + blockIdx.x;
        int slots = gridDim.x * gridDim.y * 128;
        if (tid < 128)
            for (int e = flatb * 128 + tid; e < E; e += slots)
                atomicAdd(&counts[ridx[e]], 1);
    }
    __syncthreads();
    {
        int n = tid >> 3, c4 = (tid & 7) * 4;
        if (n0 + n < N) {
            ushort4 u;
            u.x = f2bf(tile[c4][n]);
            u.y = f2bf(tile[c4 + 1][n]);
            u.z = f2bf(tile[c4 + 2][n]);
            u.w = f2bf(tile[c4 + 3][n]);
            *(ushort4*)(xtb + (size_t)(n0 + n) * CCH + c0 + c4) = u;
        }
    }
}

// ---------------- CSR build: offsets via wave scan + one atomic per wave
__global__ void make_offsets(const int* __restrict__ counts, int* __restrict__ offs,
                             int* __restrict__ total, int N) {
    int n = blockIdx.x * 256 + threadIdx.x;
    int lane = threadIdx.x & 63;
    int c = (n < N) ? counts[n] : 0;
    int s = c;
    #pragma unroll
    for (int d = 1; d < 64; d <<= 1) {
        int u = __shfl_up(s, d);
        if (lane >= d) s += u;
    }
    int base = 0;
    if (lane == 63) base = atomicAdd(total, s);
    base = __shfl(base, 63);
    if (n < N) offs[n] = base + s - c;          // exclusive start (becomes cursor)
}

// ---------------- CSR fill, XCD-partitioned: block (b&7)==p handles r-partition p.
// All offs[r] atomics and csr lines of partition p stay in XCD p's L2 ->
// stores merge in-cache, one writeback per line instead of one per store.
#define FILL_CS 4096   // edges per chunk
__global__ __launch_bounds__(256) void fill_csr_xcd(
        const int* __restrict__ ridx, const int* __restrict__ gidx,
        int* __restrict__ offs, int* __restrict__ csr, int E, int psz) {
    int part  = blockIdx.x & 7;        // round-robin -> XCD id
    int chunk = blockIdx.x >> 3;
    int e0 = chunk * FILL_CS;
    int e1 = e0 + FILL_CS; if (e1 > E) e1 = E;
    for (int e = e0 + threadIdx.x; e < e1; e += 256) {
        int r = ridx[e];
        int g = gidx[e];               // unconditional coalesced read
        if (r / psz == part) {
            int p = atomicAdd(&offs[r], 1);
            csr[p] = g;
        }
    }
}

// ---------------- gather-mean over bf16 x_t: one wave per vertex, bf16 output
__global__ __launch_bounds__(256) void gather_mean(
        const uint2* __restrict__ xtb,      // [N][32] uint2 = bf16x4 quads
        const int*   __restrict__ offs_end, // [N] (end after fill)
        const int*   __restrict__ counts,   // [N]
        const int*   __restrict__ csr,      // [E]
        ushort*      __restrict__ gmb,      // [N][128] bf16
        int N) {
    int wave = threadIdx.x >> 6;
    int l = threadIdx.x & 63;
    int lq = l & 31;          // channel quad
    int half = l >> 5;        // edge-pair half
    #pragma unroll
    for (int i = 0; i < 2; ++i) {
        int n = blockIdx.x * 8 + wave * 2 + i;
        if (n >= N) return;   // wave-uniform
        int end = __builtin_amdgcn_readfirstlane(offs_end[n]);
        int deg = __builtin_amdgcn_readfirstlane(counts[n]);
        int off = end - deg;
        float4 acc = make_float4(0.f, 0.f, 0.f, 0.f);
        int k = 0;
        for (; k + 16 <= deg; k += 16) {        // 8 outstanding 8B gathers/lane
            uint2 u[8];
            #pragma unroll
            for (int q = 0; q < 8; ++q) {
                int g = csr[off + k + 2 * q + half];
                u[q] = xtb[(size_t)g * 32 + lq];
            }
            #pragma unroll
            for (int q = 0; q < 8; ++q) {
                acc.x += bflo(u[q].x); acc.y += bfhi(u[q].x);
                acc.z += bflo(u[q].y); acc.w += bfhi(u[q].y);
            }
        }
        for (; k + 8 <= deg; k += 8) {
            uint2 u[4];
            #pragma unroll
            for (int q = 0; q < 4; ++q) {
                int g = csr[off + k + 2 * q + half];
                u[q] = xtb[(size_t)g * 32 + lq];
            }
            #pragma unroll
            for (int q = 0; q < 4; ++q) {
                acc.x += bflo(u[q].x); acc.y += bfhi(u[q].x);
                acc.z += bflo(u[q].y); acc.w += bfhi(u[q].y);
            }
        }
        for (; k + 2 <= deg; k += 2) {
            int g = csr[off + k + half];
            uint2 u = xtb[(size_t)g * 32 + lq];
            acc.x += bflo(u.x); acc.y += bfhi(u.x);
            acc.z += bflo(u.y); acc.w += bfhi(u.y);
        }
        if (k < deg && half == 0) {
            int g = csr[off + k];
            uint2 u = xtb[(size_t)g * 32 + lq];
            acc.x += bflo(u.x); acc.y += bfhi(u.x);
            acc.z += bflo(u.y); acc.w += bfhi(u.y);
        }
        acc.x += __shfl_xor(acc.x, 32);
        acc.y += __shfl_xor(acc.y, 32);
        acc.z += __shfl_xor(acc.z, 32);
        acc.w += __shfl_xor(acc.w, 32);
        float inv = (deg > 0) ? 1.f / (float)deg : 0.f;
        if (half == 0) {
            ushort4 r;
            r.x = f2bf(acc.x * inv);
            r.y = f2bf(acc.y * inv);
            r.z = f2bf(acc.z * inv);
            r.w = f2bf(acc.w * inv);
            *(ushort4*)(gmb + (size_t)n * CCH + lq * 4) = r;
        }
    }
}

// ---------------- MFMA gemm: out = mask * leaky(W_stack @ [x;gmean] + bias)
// N_TILE=64, 4 waves, each wave: 16 n-cols x 128 o-rows, K=256. No LDS, no barrier.
__global__ __launch_bounds__(256) void gemm_mfma(
        const ushort* __restrict__ wstb,    // [128][256] bf16
        const ushort* __restrict__ xtb,     // [N][128] bf16  (K 0..127)
        const ushort* __restrict__ gmb,     // [N][128] bf16  (K 128..255)
        const int*    __restrict__ counts,  // [N]
        const float*  __restrict__ bias,    // [128]
        float* __restrict__ out,            // [128][N]
        int N) {
    int t = threadIdx.x;
    int wv = t >> 6;       // wave 0..3 -> n-frag
    int l  = t & 63;
    int l15 = l & 15;      // A: M-row / B: N-col / D: N-col
    int lk  = l >> 4;      // k-group (0..3)
    int n = blockIdx.x * 64 + wv * 16 + l15;
    int nc = (n < N) ? n : (N - 1);          // clamped for loads

    f32x4 acc[8];
    #pragma unroll
    for (int mf = 0; mf < 8; ++mf) acc[mf] = (f32x4){0.f, 0.f, 0.f, 0.f};

    const ushort* brow_x = xtb + (size_t)nc * CCH + lk * 8;
    const ushort* brow_g = gmb + (size_t)nc * CCH + lk * 8;
    const ushort* arow   = wstb + (size_t)l15 * 256 + lk * 8;

    #pragma unroll
    for (int ks = 0; ks < 8; ++ks) {
        const ushort* bp = (ks < 4) ? (brow_x + ks * 32) : (brow_g + (ks - 4) * 32);
        bf16x8 b = *(const bf16x8*)bp;
        #pragma unroll
        for (int mf = 0; mf < 8; ++mf) {
            bf16x8 a = *(const bf16x8*)(arow + (size_t)mf * 16 * 256 + ks * 32);
            acc[mf] = __builtin_amdgcn_mfma_f32_16x16x32_bf16(a, b, acc[mf], 0, 0, 0);
        }
    }

    // epilogue: D row(o) = mf*16 + lk*4 + r, col(n) = lane&15
    if (n < N) {
        float m = (counts[n] > 0) ? 1.f : 0.f;
        #pragma unroll
        for (int mf = 0; mf < 8; ++mf) {
            #pragma unroll
            for (int r = 0; r < 4; ++r) {
                int o = mf * 16 + lk * 4 + r;
                float v = (acc[mf][r] + bias[o]) * m;
                v = (v >= 0.f) ? v : 0.3f * v;
                out[(size_t)o * N + n] = v;
            }
        }
    }
}

extern "C" void kernel_launch(void* const* d_in, const int* in_sizes, int n_in,
                              void* d_out, int out_size, void* d_ws, size_t ws_size,
                              hipStream_t stream) {
    const float* x      = (const float*)d_in[0];  // [1,128,N]
    const float* weight = (const float*)d_in[1];  // [128,256]
    const float* bias   = (const float*)d_in[2];  // [128]
    const int*   ridx   = (const int*)d_in[3];    // [E]
    const int*   gidx   = (const int*)d_in[4];    // [E]
    float* out = (float*)d_out;

    int N = in_sizes[0] / CCH;   // 50000
    int E = in_sizes[3];         // 800000

    char* ws = (char*)d_ws;
    size_t xtb_bytes = (((size_t)N * CCH * sizeof(ushort)) + 63) & ~(size_t)63;
    size_t n_bytes   = (((size_t)N * sizeof(int)) + 63) & ~(size_t)63;
    size_t csr_bytes = (((size_t)E * sizeof(int)) + 63) & ~(size_t)63;
    size_t w_bytes   = (((size_t)CCH * 256 * sizeof(ushort)) + 63) & ~(size_t)63;

    size_t o = 0;
    ushort* xtb   = (ushort*)(ws + o); o += xtb_bytes;
    int*    counts= (int*)   (ws + o); o += n_bytes;
    int*    total = (int*)   (ws + o); o += 64;
    int*    offs  = (int*)   (ws + o); o += n_bytes;
    int*    csr   = (int*)   (ws + o); o += csr_bytes;
    ushort* wstb  = (ushort*)(ws + o); o += w_bytes;
    ushort* gmb   = (ushort*)(ws + o);

    // 1. weights prep (bf16 W_stack) + zero counts/total
    prep_zero<<<128, 256, 0, stream>>>(weight, wstb, counts, N + 16);

    // 2. transpose to bf16 + fused histogram
    dim3 tg((N + 31) / 32, CCH / 32);
    transpose_hist<<<tg, 256, 0, stream>>>(x, xtb, ridx, counts, N, E);

    // 3-4. offsets + XCD-partitioned CSR fill
    int nblocks = (N + 255) / 256;
    make_offsets<<<nblocks, 256, 0, stream>>>(counts, offs, total, N);
    int psz = (N + 7) / 8;
    int nchunks = (E + FILL_CS - 1) / FILL_CS;
    fill_csr_xcd<<<nchunks * 8, 256, 0, stream>>>(ridx, gidx, offs, csr, E, psz);
    // offs[n] is now segment END; start = end - counts[n]

    // 5. gather-mean (bf16 reads, fp32 accumulate, bf16 output)
    gather_mean<<<(N + 7) / 8, 256, 0, stream>>>(
        (const uint2*)xtb, offs, counts, csr, gmb, N);

    // 6. single bf16 MFMA GEMM + bias + mask + leaky
    gemm_mfma<<<(N + 63) / 64, 256, 0, stream>>>(
        wstb, xtb, gmb, counts, bias, out, N);
}